// Round 2
// baseline (511.619 us; speedup 1.0000x reference)
//
#include <hip/hip_runtime.h>
#include <hip/hip_bf16.h>

#define HID 1024
#define NH 16
#define HEAD 64
#define WIN 256
#define SEQ 4096
#define BATCH 4
#define NROWS (BATCH * SEQ)   // 16384
#define LN_EPS 1e-5f

typedef unsigned short u16;
typedef __bf16 bf16x8 __attribute__((ext_vector_type(8)));
typedef float f32x4 __attribute__((ext_vector_type(4)));

static __device__ inline float bfu(u16 u) {
    union { unsigned int i; float f; } x;
    x.i = ((unsigned int)u) << 16;
    return x.f;
}

static __device__ inline u16 f2bf(float f) {
    union { float f; unsigned int i; } x;
    x.f = f;
    unsigned int lsb = (x.i >> 16) & 1u;
    x.i += 0x7fffu + lsb;   // round-to-nearest-even
    return (u16)(x.i >> 16);
}

// ---------------------------------------------------------------- weights f32 -> bf16
__global__ __launch_bounds__(256) void convert_weights(
    const float* __restrict__ wq, const float* __restrict__ wk,
    const float* __restrict__ wv, const float* __restrict__ wp,
    u16* __restrict__ o)
{
    int i = blockIdx.x * 256 + threadIdx.x;
    const int n = 1024 * 1024;
    if (i < n) {
        o[i]         = f2bf(wq[i]);
        o[n + i]     = f2bf(wk[i]);
        o[2 * n + i] = f2bf(wv[i]);
        o[3 * n + i] = f2bf(wp[i]);
    }
}

// ---------------------------------------------------------------- LN1: f32 in -> bf16 out
__global__ __launch_bounds__(256) void ln1_kernel(
    const float* __restrict__ x, const float* __restrict__ g,
    const float* __restrict__ b, u16* __restrict__ out)
{
    int row = blockIdx.x;
    int t = threadIdx.x;
    float4 v = ((const float4*)(x + (size_t)row * HID))[t];
    float s  = v.x + v.y + v.z + v.w;
    float ss = v.x * v.x + v.y * v.y + v.z * v.z + v.w * v.w;
    __shared__ float red[8];
    #pragma unroll
    for (int off = 32; off; off >>= 1) { s += __shfl_down(s, off); ss += __shfl_down(ss, off); }
    int wave = t >> 6, lane = t & 63;
    if (lane == 0) { red[wave] = s; red[4 + wave] = ss; }
    __syncthreads();
    float S  = red[0] + red[1] + red[2] + red[3];
    float SS = red[4] + red[5] + red[6] + red[7];
    float mean = S * (1.f / HID);
    float var  = SS * (1.f / HID) - mean * mean;
    float inv  = rsqrtf(var + LN_EPS);
    float4 gv = ((const float4*)g)[t];
    float4 bv = ((const float4*)b)[t];
    ushort4 o;
    o.x = f2bf((v.x - mean) * inv * gv.x + bv.x);
    o.y = f2bf((v.y - mean) * inv * gv.y + bv.y);
    o.z = f2bf((v.z - mean) * inv * gv.z + bv.z);
    o.w = f2bf((v.w - mean) * inv * gv.w + bv.w);
    ((ushort4*)(out + (size_t)row * HID))[t] = o;
}

// ---------------------------------------------------------------- bf16 GEMM: C[M,N] = A[M,K] @ W[N,K]^T
// 128x128 tile, BK=32, 4 waves (2x2), m97 structure with global_load_lds width=16,
// T3 minimum 2-phase: one vmcnt(0)+barrier per K-tile.
__global__ __launch_bounds__(256) void gemm_bt(
    const u16* __restrict__ A, const u16* __restrict__ W,
    u16* __restrict__ C, int M, int N, int K, int ldc)
{
    __shared__ __align__(16) u16 sA[2][128 * 32];
    __shared__ __align__(16) u16 sB[2][128 * 32];

    int t = threadIdx.x;
    int bm = blockIdx.x, bn = blockIdx.y;
    int wave = t >> 6, lane = t & 63;
    int wr = wave >> 1, wc = wave & 1;

    f32x4 acc[4][4];
    #pragma unroll
    for (int m = 0; m < 4; ++m)
        #pragma unroll
        for (int n = 0; n < 4; ++n) {
            f32x4 z = {0.f, 0.f, 0.f, 0.f};
            acc[m][n] = z;
        }

    const int nk = K >> 5;

    auto stage = [&](int buf, int kt) {
        int k0 = kt << 5;
        #pragma unroll
        for (int i = 0; i < 2; ++i) {
            int ch = i * 256 + t;
            int row = ch >> 2, kc = (ch & 3) << 3;
            const u16* ga = A + (size_t)(bm * 128 + row) * K + k0 + kc;
            __builtin_amdgcn_global_load_lds(
                (const __attribute__((address_space(1))) void*)ga,
                (__attribute__((address_space(3))) void*)&sA[buf][ch * 8], 16, 0, 0);
            const u16* gb = W + (size_t)(bn * 128 + row) * K + k0 + kc;
            __builtin_amdgcn_global_load_lds(
                (const __attribute__((address_space(1))) void*)gb,
                (__attribute__((address_space(3))) void*)&sB[buf][ch * 8], 16, 0, 0);
        }
    };

    stage(0, 0);
    int cur = 0;
    for (int kt = 0; kt < nk; ++kt) {
        asm volatile("s_waitcnt vmcnt(0)" ::: "memory");
        __syncthreads();
        if (kt + 1 < nk) stage(cur ^ 1, kt + 1);

        int arow = wr * 64 + (lane & 15);
        int brow = wc * 64 + (lane & 15);
        int kg = (lane >> 4) << 3;
        bf16x8 af[4], bfv[4];
        #pragma unroll
        for (int m = 0; m < 4; ++m)
            af[m] = *(const bf16x8*)&sA[cur][(arow + m * 16) * 32 + kg];
        #pragma unroll
        for (int n = 0; n < 4; ++n)
            bfv[n] = *(const bf16x8*)&sB[cur][(brow + n * 16) * 32 + kg];
        #pragma unroll
        for (int m = 0; m < 4; ++m)
            #pragma unroll
            for (int n = 0; n < 4; ++n)
                acc[m][n] = __builtin_amdgcn_mfma_f32_16x16x32_bf16(af[m], bfv[n], acc[m][n], 0, 0, 0);

        cur ^= 1;
    }

    #pragma unroll
    for (int m = 0; m < 4; ++m) {
        int row0 = bm * 128 + wr * 64 + m * 16 + ((lane >> 4) << 2);
        #pragma unroll
        for (int n = 0; n < 4; ++n) {
            int col = bn * 128 + wc * 64 + n * 16 + (lane & 15);
            #pragma unroll
            for (int r = 0; r < 4; ++r)
                C[(size_t)(row0 + r) * ldc + col] = f2bf(acc[m][n][r]);
        }
    }
}

// ---------------------------------------------------------------- windowed additive attention
// block = (chunk c, head h, batch b), 256 threads (4 waves).
// win(c,j) = prefix_c(j) + total_{c-1} - prefix_{c-1}(j); chunk-local scans in LDS.
__global__ __launch_bounds__(256) void attn_win(
    const u16* __restrict__ x, int xstride,
    const float* __restrict__ vec,
    const float* __restrict__ mask,
    u16* __restrict__ out)
{
    int c = blockIdx.x, h = blockIdx.y, b = blockIdx.z;
    __shared__ __align__(16) u16 xl[2][WIN][HEAD];   // 64 KB
    __shared__ float aw[2][WIN];                     // exp weights
    __shared__ float sts[2][4][HEAD];                // sub-block sums of a*x
    __shared__ float stz[2][4];                      // sub-block sums of a

    int t = threadIdx.x, wave = t >> 6, lane = t & 63;
    bool havePrev = (c > 0);

    // stage chunks c-1 (cc=0) and c (cc=1) into LDS (128B rows, coalesced 16B pieces)
    int pstart = havePrev ? 0 : 2048;
    for (int p = pstart + t; p < 4096; p += 256) {
        int cc = p >> 11, rem = p & 2047, j = rem >> 3, q = rem & 7;
        int seq = (c - 1 + cc) * WIN + j;
        const uint4* src = (const uint4*)(x + (size_t)(b * SEQ + seq) * xstride + h * HEAD + q * 8);
        *(uint4*)(&xl[cc][j][q * 8]) = *src;
    }
    if (!havePrev) {
        uint4 z4 = make_uint4(0u, 0u, 0u, 0u);
        for (int i = t; i < 2048; i += 256) ((uint4*)(&xl[0][0][0]))[i] = z4;
        for (int i = t; i < WIN; i += 256) aw[0][i] = 0.f;
    }
    __syncthreads();

    // logits: one row per wave-iteration, lane=dim, butterfly reduce
    float vecv = vec[h * HEAD + lane];
    int rstart = havePrev ? wave : (256 + wave);
    for (int r = rstart; r < 512; r += 4) {
        int cc = r >> 8, j = r & 255;
        float s = bfu(xl[cc][j][lane]) * vecv;
        #pragma unroll
        for (int off = 32; off; off >>= 1) s += __shfl_xor(s, off);
        int seq = (c - 1 + cc) * WIN + j;
        float ma = (1.0f - mask[b * SEQ + seq]) * -10000.0f;
        float a = expf(s * 0.125f + ma);
        if (lane == 0) aw[cc][j] = a;
    }
    __syncthreads();

    // step A: sub-block totals (wave w owns rows [64w,64w+64) of both chunks)
    float s0 = 0.f, s1 = 0.f, z0 = 0.f, z1 = 0.f;
    #pragma unroll 8
    for (int jj = 0; jj < 64; ++jj) {
        int j = (wave << 6) + jj;
        float ap = aw[0][j], ac = aw[1][j];
        s0 += ap * bfu(xl[0][j][lane]);
        s1 += ac * bfu(xl[1][j][lane]);
        z0 += ap; z1 += ac;
    }
    sts[0][wave][lane] = s0;
    sts[1][wave][lane] = s1;
    if (lane == 0) { stz[0][wave] = z0; stz[1][wave] = z1; }
    __syncthreads();

    // step B: carries + previous-chunk totals
    float cs0 = 0.f, cs1 = 0.f, cz0 = 0.f, cz1 = 0.f, tots = 0.f, totz = 0.f;
    #pragma unroll
    for (int w2 = 0; w2 < 4; ++w2) {
        float sp = sts[0][w2][lane];
        float zp = stz[0][w2];
        tots += sp; totz += zp;
        if (w2 < wave) {
            cs0 += sp; cz0 += zp;
            cs1 += sts[1][w2][lane];
            cz1 += stz[1][w2];
        }
    }

    // step C: rescan with carries, emit windowed average
    float rp = cs0, rc = cs1, rzp = cz0, rzc = cz1;
    size_t obase = (size_t)(b * SEQ + c * WIN) * HID + h * HEAD + lane;
    #pragma unroll 8
    for (int jj = 0; jj < 64; ++jj) {
        int j = (wave << 6) + jj;
        float ap = aw[0][j], ac = aw[1][j];
        rp  += ap * bfu(xl[0][j][lane]);
        rc  += ac * bfu(xl[1][j][lane]);
        rzp += ap; rzc += ac;
        float swin = rc + tots - rp;
        float zwin = rzc + totz - rzp;
        out[obase + (size_t)j * HID] = f2bf(swin / zwin);
    }
}

// ---------------------------------------------------------------- residual + LN2
// pq (pooled_q @ Wp.T) lives in qkv cols 0..1023; keys in cols 1024..2047.
// residual (f32) goes to d_out; mixed (bf16) overwrites h in place.
__global__ __launch_bounds__(256) void resid_ln2(
    const u16* h, const u16* __restrict__ qkv,
    const float* __restrict__ g, const float* __restrict__ b,
    float* __restrict__ residual, u16* mixed)
{
    int row = blockIdx.x;
    int t = threadIdx.x;
    ushort4 h4 = ((const ushort4*)(h + (size_t)row * HID))[t];
    ushort4 p4 = ((const ushort4*)(qkv + (size_t)row * 3072))[t];
    ushort4 k4 = ((const ushort4*)(qkv + (size_t)row * 3072 + 1024))[t];
    float r0 = bfu(h4.x) + bfu(p4.x) * bfu(k4.x);
    float r1 = bfu(h4.y) + bfu(p4.y) * bfu(k4.y);
    float r2 = bfu(h4.z) + bfu(p4.z) * bfu(k4.z);
    float r3 = bfu(h4.w) + bfu(p4.w) * bfu(k4.w);
    ((float4*)(residual + (size_t)row * HID))[t] = make_float4(r0, r1, r2, r3);

    float s  = r0 + r1 + r2 + r3;
    float ss = r0 * r0 + r1 * r1 + r2 * r2 + r3 * r3;
    __shared__ float red[8];
    #pragma unroll
    for (int off = 32; off; off >>= 1) { s += __shfl_down(s, off); ss += __shfl_down(ss, off); }
    int wave = t >> 6, lane = t & 63;
    if (lane == 0) { red[wave] = s; red[4 + wave] = ss; }
    __syncthreads();
    float S  = red[0] + red[1] + red[2] + red[3];
    float SS = red[4] + red[5] + red[6] + red[7];
    float mean = S * (1.f / HID);
    float var  = SS * (1.f / HID) - mean * mean;
    float inv  = rsqrtf(var + LN_EPS);
    float4 gv = ((const float4*)g)[t];
    float4 bv = ((const float4*)b)[t];
    ushort4 o;
    o.x = f2bf((r0 - mean) * inv * gv.x + bv.x);
    o.y = f2bf((r1 - mean) * inv * gv.y + bv.y);
    o.z = f2bf((r2 - mean) * inv * gv.z + bv.z);
    o.w = f2bf((r3 - mean) * inv * gv.w + bv.w);
    ((ushort4*)(mixed + (size_t)row * HID))[t] = o;
}

// ---------------------------------------------------------------- out += pooled_k * values (in place; out holds residual)
__global__ __launch_bounds__(256) void final_kernel(
    float* out, const u16* __restrict__ pk,
    const u16* __restrict__ qkv, int total4)
{
    for (int i = blockIdx.x * blockDim.x + threadIdx.x; i < total4; i += gridDim.x * blockDim.x) {
        int e = i * 4;
        int r = e >> 10;
        int cc = e & 1023;
        float4 rv = ((const float4*)out)[i];
        ushort4 pv = ((const ushort4*)pk)[i];
        ushort4 vv = *(const ushort4*)(qkv + (size_t)r * 3072 + 2048 + cc);
        float4 o;
        o.x = rv.x + bfu(pv.x) * bfu(vv.x);
        o.y = rv.y + bfu(pv.y) * bfu(vv.y);
        o.z = rv.z + bfu(pv.z) * bfu(vv.z);
        o.w = rv.w + bfu(pv.w) * bfu(vv.w);
        ((float4*)out)[i] = o;
    }
}

extern "C" void kernel_launch(void* const* d_in, const int* in_sizes, int n_in,
                              void* d_out, int out_size, void* d_ws, size_t ws_size,
                              hipStream_t stream)
{
    const float* hidden = (const float*)d_in[0];
    const float* mask   = (const float*)d_in[1];
    const float* Wq     = (const float*)d_in[2];
    const float* Wk     = (const float*)d_in[3];
    const float* Wv     = (const float*)d_in[4];
    const float* Wp     = (const float*)d_in[5];
    const float* qa     = (const float*)d_in[6];
    const float* ka     = (const float*)d_in[7];
    const float* g1     = (const float*)d_in[8];
    const float* b1     = (const float*)d_in[9];
    const float* g2     = (const float*)d_in[10];
    const float* b2     = (const float*)d_in[11];
    float* out = (float*)d_out;

    // workspace layout: 8 + 32 + 96 + 32 = 168 MB
    char* ws = (char*)d_ws;
    u16* wbf = (u16*)ws;       ws += (size_t)4 * 1024 * 1024 * 2;     //  8 MB  Wq|Wk|Wv|Wp bf16
    u16* hbf = (u16*)ws;       ws += (size_t)NROWS * HID * 2;         // 32 MB  h (later: mixed, in place)
    u16* qkv = (u16*)ws;       ws += (size_t)NROWS * 3072 * 2;        // 96 MB  q|k|v rows (q-cols reused for pq@Wp.T)
    u16* pooled = (u16*)ws;                                           // 32 MB  pooled_q then pooled_k

    convert_weights<<<4096, 256, 0, stream>>>(Wq, Wk, Wv, Wp, wbf);
    ln1_kernel<<<NROWS, 256, 0, stream>>>(hidden, g1, b1, hbf);
    gemm_bt<<<dim3(128, 24), 256, 0, stream>>>(hbf, wbf, qkv, NROWS, 3072, HID, 3072);
    attn_win<<<dim3(SEQ / WIN, NH, BATCH), 256, 0, stream>>>(qkv, 3072, qa, mask, pooled);
    // pooled_q @ Wp.T -> qkv cols 0..1023 (q is dead)
    gemm_bt<<<dim3(128, 8), 256, 0, stream>>>(pooled, wbf + (size_t)3 * 1024 * 1024, qkv,
                                              NROWS, HID, HID, 3072);
    resid_ln2<<<NROWS, 256, 0, stream>>>(hbf, qkv, g2, b2, out, hbf);
    attn_win<<<dim3(SEQ / WIN, NH, BATCH), 256, 0, stream>>>(hbf, HID, ka, mask, pooled);
    final_kernel<<<2048, 256, 0, stream>>>(out, pooled, qkv, NROWS * HID / 4);
}

// Round 3
// 333.377 us; speedup vs baseline: 1.5347x; 1.5347x over previous
//
#include <hip/hip_runtime.h>
#include <hip/hip_bf16.h>

#define HID 1024
#define NH 16
#define HEAD 64
#define WIN 256
#define SEQ 4096
#define BATCH 4
#define NROWS (BATCH * SEQ)   // 16384
#define LN_EPS 1e-5f

typedef unsigned short u16;
typedef __bf16 bf16x8 __attribute__((ext_vector_type(8)));
typedef float f32x4 __attribute__((ext_vector_type(4)));

static __device__ inline float bfu(u16 u) {
    union { unsigned int i; float f; } x;
    x.i = ((unsigned int)u) << 16;
    return x.f;
}

static __device__ inline u16 f2bf(float f) {
    union { float f; unsigned int i; } x;
    x.f = f;
    unsigned int lsb = (x.i >> 16) & 1u;
    x.i += 0x7fffu + lsb;   // round-to-nearest-even
    return (u16)(x.i >> 16);
}

// ---------------------------------------------------------------- weights f32 -> bf16
__global__ __launch_bounds__(256) void convert_weights(
    const float* __restrict__ wq, const float* __restrict__ wk,
    const float* __restrict__ wv, const float* __restrict__ wp,
    u16* __restrict__ o)
{
    int i = blockIdx.x * 256 + threadIdx.x;
    const int n = 1024 * 1024;
    if (i < n) {
        o[i]         = f2bf(wq[i]);
        o[n + i]     = f2bf(wk[i]);
        o[2 * n + i] = f2bf(wv[i]);
        o[3 * n + i] = f2bf(wp[i]);
    }
}

// ---------------------------------------------------------------- LN1: f32 in -> bf16 out
__global__ __launch_bounds__(256) void ln1_kernel(
    const float* __restrict__ x, const float* __restrict__ g,
    const float* __restrict__ b, u16* __restrict__ out)
{
    int row = blockIdx.x;
    int t = threadIdx.x;
    float4 v = ((const float4*)(x + (size_t)row * HID))[t];
    float s  = v.x + v.y + v.z + v.w;
    float ss = v.x * v.x + v.y * v.y + v.z * v.z + v.w * v.w;
    __shared__ float red[8];
    #pragma unroll
    for (int off = 32; off; off >>= 1) { s += __shfl_down(s, off); ss += __shfl_down(ss, off); }
    int wave = t >> 6, lane = t & 63;
    if (lane == 0) { red[wave] = s; red[4 + wave] = ss; }
    __syncthreads();
    float S  = red[0] + red[1] + red[2] + red[3];
    float SS = red[4] + red[5] + red[6] + red[7];
    float mean = S * (1.f / HID);
    float var  = SS * (1.f / HID) - mean * mean;
    float inv  = rsqrtf(var + LN_EPS);
    float4 gv = ((const float4*)g)[t];
    float4 bv = ((const float4*)b)[t];
    ushort4 o;
    o.x = f2bf((v.x - mean) * inv * gv.x + bv.x);
    o.y = f2bf((v.y - mean) * inv * gv.y + bv.y);
    o.z = f2bf((v.z - mean) * inv * gv.z + bv.z);
    o.w = f2bf((v.w - mean) * inv * gv.w + bv.w);
    ((ushort4*)(out + (size_t)row * HID))[t] = o;
}

// ---------------------------------------------------------------- bf16 GEMM: C[M,N] = A[M,K] @ W[N,K]^T
__global__ __launch_bounds__(256) void gemm_bt(
    const u16* __restrict__ A, const u16* __restrict__ W,
    u16* __restrict__ C, int M, int N, int K, int ldc)
{
    __shared__ __align__(16) u16 sA[2][128 * 32];
    __shared__ __align__(16) u16 sB[2][128 * 32];

    int t = threadIdx.x;
    int bm = blockIdx.x, bn = blockIdx.y;
    int wave = t >> 6, lane = t & 63;
    int wr = wave >> 1, wc = wave & 1;

    f32x4 acc[4][4];
    #pragma unroll
    for (int m = 0; m < 4; ++m)
        #pragma unroll
        for (int n = 0; n < 4; ++n) {
            f32x4 z = {0.f, 0.f, 0.f, 0.f};
            acc[m][n] = z;
        }

    const int nk = K >> 5;

    auto stage = [&](int buf, int kt) {
        int k0 = kt << 5;
        #pragma unroll
        for (int i = 0; i < 2; ++i) {
            int ch = i * 256 + t;
            int row = ch >> 2, kc = (ch & 3) << 3;
            const u16* ga = A + (size_t)(bm * 128 + row) * K + k0 + kc;
            __builtin_amdgcn_global_load_lds(
                (const __attribute__((address_space(1))) void*)ga,
                (__attribute__((address_space(3))) void*)&sA[buf][ch * 8], 16, 0, 0);
            const u16* gb = W + (size_t)(bn * 128 + row) * K + k0 + kc;
            __builtin_amdgcn_global_load_lds(
                (const __attribute__((address_space(1))) void*)gb,
                (__attribute__((address_space(3))) void*)&sB[buf][ch * 8], 16, 0, 0);
        }
    };

    stage(0, 0);
    int cur = 0;
    for (int kt = 0; kt < nk; ++kt) {
        asm volatile("s_waitcnt vmcnt(0)" ::: "memory");
        __syncthreads();
        if (kt + 1 < nk) stage(cur ^ 1, kt + 1);

        int arow = wr * 64 + (lane & 15);
        int brow = wc * 64 + (lane & 15);
        int kg = (lane >> 4) << 3;
        bf16x8 af[4], bfv[4];
        #pragma unroll
        for (int m = 0; m < 4; ++m)
            af[m] = *(const bf16x8*)&sA[cur][(arow + m * 16) * 32 + kg];
        #pragma unroll
        for (int n = 0; n < 4; ++n)
            bfv[n] = *(const bf16x8*)&sB[cur][(brow + n * 16) * 32 + kg];
        #pragma unroll
        for (int m = 0; m < 4; ++m)
            #pragma unroll
            for (int n = 0; n < 4; ++n)
                acc[m][n] = __builtin_amdgcn_mfma_f32_16x16x32_bf16(af[m], bfv[n], acc[m][n], 0, 0, 0);

        cur ^= 1;
    }

    #pragma unroll
    for (int m = 0; m < 4; ++m) {
        int row0 = bm * 128 + wr * 64 + m * 16 + ((lane >> 4) << 2);
        #pragma unroll
        for (int n = 0; n < 4; ++n) {
            int col = bn * 128 + wc * 64 + n * 16 + (lane & 15);
            #pragma unroll
            for (int r = 0; r < 4; ++r)
                C[(size_t)(row0 + r) * ldc + col] = f2bf(acc[m][n][r]);
        }
    }
}

// ---------------------------------------------------------------- logits: aw[b][h][s] = exp(dot(x_row_head, vec_head)/8 + mask_add)
// one thread = one (row, head); zero cross-lane ops.
__global__ __launch_bounds__(256) void logits_kernel(
    const u16* __restrict__ x, int xstride,
    const float* __restrict__ vec, const float* __restrict__ mask,
    float* __restrict__ aw)
{
    int h = blockIdx.y, b = blockIdx.z;
    int s = blockIdx.x * 256 + threadIdx.x;
    __shared__ float vl[HEAD];
    if (threadIdx.x < HEAD) vl[threadIdx.x] = vec[h * HEAD + threadIdx.x];
    __syncthreads();
    const uint4* xr = (const uint4*)(x + ((size_t)(b * SEQ + s)) * xstride + h * HEAD);
    float dot = 0.f;
    #pragma unroll
    for (int i = 0; i < 8; ++i) {
        uint4 v = xr[i];
        const u16* p = (const u16*)&v;
        #pragma unroll
        for (int j = 0; j < 8; ++j) dot += bfu(p[j]) * vl[i * 8 + j];
    }
    float ma = (1.0f - mask[b * SEQ + s]) * -10000.0f;
    aw[((size_t)b * NH + h) * SEQ + s] = expf(dot * 0.125f + ma);
}

// ---------------------------------------------------------------- windowed scan attention
// block = (chunk c, head h, batch b), 256 threads (4 waves). No x staging (L2-resident);
// aw precomputed. win(c,j) = prefix_c(j) + total_{c-1} - prefix_{c-1}(j).
__global__ __launch_bounds__(256) void attn_win(
    const u16* __restrict__ x, int xstride,
    const float* __restrict__ aw_g,   // [B,NH,SEQ]
    u16* __restrict__ out)
{
    int c = blockIdx.x, h = blockIdx.y, b = blockIdx.z;
    __shared__ float awl[2][WIN];
    __shared__ float sts[2][4][HEAD];
    __shared__ float stz[2][4];

    int t = threadIdx.x, wave = t >> 6, lane = t & 63;
    bool havePrev = (c > 0);

    const float* awb = aw_g + ((size_t)b * NH + h) * SEQ;
    for (int i = t; i < 2 * WIN; i += 256) {
        int cc = i >> 8, j = i & (WIN - 1);
        float v = 0.f;
        if (cc == 1) v = awb[c * WIN + j];
        else if (havePrev) v = awb[(c - 1) * WIN + j];
        awl[cc][j] = v;
    }
    __syncthreads();

    const u16* xb = x + (size_t)b * SEQ * xstride + h * HEAD + lane;
    int jp0 = (havePrev ? (c - 1) : c) * WIN;   // clamped when c==0 (aw=0 kills it)
    int jc0 = c * WIN;
    int j0 = wave << 6;

    // step A: per-wave sub-block totals over rows [j0, j0+64) of both chunks
    float s0 = 0.f, s1 = 0.f, z0 = 0.f, z1 = 0.f;
    #pragma unroll 8
    for (int jj = 0; jj < 64; ++jj) {
        int j = j0 + jj;
        float ap = awl[0][j], ac = awl[1][j];
        float xp = bfu(xb[(size_t)(jp0 + j) * xstride]);
        float xc = bfu(xb[(size_t)(jc0 + j) * xstride]);
        s0 += ap * xp; z0 += ap;
        s1 += ac * xc; z1 += ac;
    }
    sts[0][wave][lane] = s0;
    sts[1][wave][lane] = s1;
    if (lane == 0) { stz[0][wave] = z0; stz[1][wave] = z1; }
    __syncthreads();

    // step B: carries + chunk-(c-1) totals
    float cs0 = 0.f, cs1 = 0.f, cz0 = 0.f, cz1 = 0.f, tots = 0.f, totz = 0.f;
    #pragma unroll
    for (int w2 = 0; w2 < 4; ++w2) {
        float sp = sts[0][w2][lane], zp = stz[0][w2];
        tots += sp; totz += zp;
        if (w2 < wave) {
            cs0 += sp; cz0 += zp;
            cs1 += sts[1][w2][lane]; cz1 += stz[1][w2];
        }
    }

    // step C: rescan with carries, emit windowed average
    float rp = cs0, rc = cs1, rzp = cz0, rzc = cz1;
    size_t obase = ((size_t)b * SEQ + c * WIN) * HID + h * HEAD + lane;
    #pragma unroll 8
    for (int jj = 0; jj < 64; ++jj) {
        int j = j0 + jj;
        float ap = awl[0][j], ac = awl[1][j];
        float xp = bfu(xb[(size_t)(jp0 + j) * xstride]);
        float xc = bfu(xb[(size_t)(jc0 + j) * xstride]);
        rp += ap * xp; rzp += ap;
        rc += ac * xc; rzc += ac;
        float swin = rc + tots - rp;
        float zwin = rzc + totz - rzp;
        out[obase + (size_t)j * HID] = f2bf(swin / zwin);
    }
}

// ---------------------------------------------------------------- residual + LN2 + fused key-attn logits
// pq lives in qkv cols 0..1023; keys in cols 1024..2047.
// residual (f32) -> d_out; mixed (bf16) -> hbf in place; aw2[b][h][s] logits for 2nd attention.
__global__ __launch_bounds__(256) void resid_ln2(
    const u16* h, const u16* __restrict__ qkv,
    const float* __restrict__ g, const float* __restrict__ b,
    const float* __restrict__ ka, const float* __restrict__ mask,
    float* __restrict__ residual, u16* mixed, float* __restrict__ aw2)
{
    int row = blockIdx.x;
    int t = threadIdx.x;
    ushort4 h4 = ((const ushort4*)(h + (size_t)row * HID))[t];
    ushort4 p4 = ((const ushort4*)(qkv + (size_t)row * 3072))[t];
    ushort4 k4 = ((const ushort4*)(qkv + (size_t)row * 3072 + 1024))[t];
    float r0 = bfu(h4.x) + bfu(p4.x) * bfu(k4.x);
    float r1 = bfu(h4.y) + bfu(p4.y) * bfu(k4.y);
    float r2 = bfu(h4.z) + bfu(p4.z) * bfu(k4.z);
    float r3 = bfu(h4.w) + bfu(p4.w) * bfu(k4.w);
    ((float4*)(residual + (size_t)row * HID))[t] = make_float4(r0, r1, r2, r3);

    float s  = r0 + r1 + r2 + r3;
    float ss = r0 * r0 + r1 * r1 + r2 * r2 + r3 * r3;
    __shared__ float red[8];
    #pragma unroll
    for (int off = 32; off; off >>= 1) { s += __shfl_down(s, off); ss += __shfl_down(ss, off); }
    int wave = t >> 6, lane = t & 63;
    if (lane == 0) { red[wave] = s; red[4 + wave] = ss; }
    __syncthreads();
    float S  = red[0] + red[1] + red[2] + red[3];
    float SS = red[4] + red[5] + red[6] + red[7];
    float mean = S * (1.f / HID);
    float var  = SS * (1.f / HID) - mean * mean;
    float inv  = rsqrtf(var + LN_EPS);
    float4 gv = ((const float4*)g)[t];
    float4 bv = ((const float4*)b)[t];
    float n0 = (r0 - mean) * inv * gv.x + bv.x;
    float n1 = (r1 - mean) * inv * gv.y + bv.y;
    float n2 = (r2 - mean) * inv * gv.z + bv.z;
    float n3 = (r3 - mean) * inv * gv.w + bv.w;
    ushort4 o;
    o.x = f2bf(n0); o.y = f2bf(n1); o.z = f2bf(n2); o.w = f2bf(n3);
    ((ushort4*)(mixed + (size_t)row * HID))[t] = o;

    // fused logits for the second attention: head = t>>4 (64 cols per head, 4 cols per thread)
    float4 kv = ((const float4*)ka)[t];
    float partial = n0 * kv.x + n1 * kv.y + n2 * kv.z + n3 * kv.w;
    partial += __shfl_xor(partial, 1);
    partial += __shfl_xor(partial, 2);
    partial += __shfl_xor(partial, 4);
    partial += __shfl_xor(partial, 8);
    if ((t & 15) == 0) {
        int hh = t >> 4;
        int bb = row >> 12, sl = row & (SEQ - 1);
        float ma = (1.0f - mask[row]) * -10000.0f;
        aw2[((size_t)bb * NH + hh) * SEQ + sl] = expf(partial * 0.125f + ma);
    }
}

// ---------------------------------------------------------------- out += pooled_k * values (in place)
__global__ __launch_bounds__(256) void final_kernel(
    float* out, const u16* __restrict__ pk,
    const u16* __restrict__ qkv, int total4)
{
    for (int i = blockIdx.x * blockDim.x + threadIdx.x; i < total4; i += gridDim.x * blockDim.x) {
        int e = i * 4;
        int r = e >> 10;
        int cc = e & 1023;
        float4 rv = ((const float4*)out)[i];
        ushort4 pv = ((const ushort4*)pk)[i];
        ushort4 vv = *(const ushort4*)(qkv + (size_t)r * 3072 + 2048 + cc);
        float4 o;
        o.x = rv.x + bfu(pv.x) * bfu(vv.x);
        o.y = rv.y + bfu(pv.y) * bfu(vv.y);
        o.z = rv.z + bfu(pv.z) * bfu(vv.z);
        o.w = rv.w + bfu(pv.w) * bfu(vv.w);
        ((float4*)out)[i] = o;
    }
}

extern "C" void kernel_launch(void* const* d_in, const int* in_sizes, int n_in,
                              void* d_out, int out_size, void* d_ws, size_t ws_size,
                              hipStream_t stream)
{
    const float* hidden = (const float*)d_in[0];
    const float* mask   = (const float*)d_in[1];
    const float* Wq     = (const float*)d_in[2];
    const float* Wk     = (const float*)d_in[3];
    const float* Wv     = (const float*)d_in[4];
    const float* Wp     = (const float*)d_in[5];
    const float* qa     = (const float*)d_in[6];
    const float* ka     = (const float*)d_in[7];
    const float* g1     = (const float*)d_in[8];
    const float* b1     = (const float*)d_in[9];
    const float* g2     = (const float*)d_in[10];
    const float* b2     = (const float*)d_in[11];
    float* out = (float*)d_out;

    // workspace: 8 + 32 + 96 + 32 + 1 + 1 = 170 MB
    char* ws = (char*)d_ws;
    u16* wbf = (u16*)ws;       ws += (size_t)4 * 1024 * 1024 * 2;     //  8 MB  Wq|Wk|Wv|Wp bf16
    u16* hbf = (u16*)ws;       ws += (size_t)NROWS * HID * 2;         // 32 MB  h (later: mixed, in place)
    u16* qkv = (u16*)ws;       ws += (size_t)NROWS * 3072 * 2;        // 96 MB  q|k|v (q-cols reused for pq@Wp.T)
    u16* pooled = (u16*)ws;    ws += (size_t)NROWS * HID * 2;         // 32 MB  pooled_q then pooled_k
    float* aw1 = (float*)ws;   ws += (size_t)BATCH * NH * SEQ * 4;    //  1 MB
    float* aw2 = (float*)ws;                                          //  1 MB

    convert_weights<<<4096, 256, 0, stream>>>(Wq, Wk, Wv, Wp, wbf);
    ln1_kernel<<<NROWS, 256, 0, stream>>>(hidden, g1, b1, hbf);
    gemm_bt<<<dim3(128, 24), 256, 0, stream>>>(hbf, wbf, qkv, NROWS, 3072, HID, 3072);
    logits_kernel<<<dim3(SEQ / 256, NH, BATCH), 256, 0, stream>>>(qkv, 3072, qa, mask, aw1);
    attn_win<<<dim3(SEQ / WIN, NH, BATCH), 256, 0, stream>>>(qkv, 3072, aw1, pooled);
    // pooled_q @ Wp.T -> qkv cols 0..1023 (q is dead)
    gemm_bt<<<dim3(128, 8), 256, 0, stream>>>(pooled, wbf + (size_t)3 * 1024 * 1024, qkv,
                                              NROWS, HID, HID, 3072);
    resid_ln2<<<NROWS, 256, 0, stream>>>(hbf, qkv, g2, b2, ka, mask, out, hbf, aw2);
    attn_win<<<dim3(SEQ / WIN, NH, BATCH), 256, 0, stream>>>(hbf, HID, aw2, pooled);
    final_kernel<<<2048, 256, 0, stream>>>(out, pooled, qkv, NROWS * HID / 4);
}